// Round 22
// baseline (85.980 us; speedup 1.0000x reference)
//
#include <hip/hip_runtime.h>

// GAT layer, N=8192, IN_F=128, OUT_F=64.
//   Wh = h@W; Wh1 = Wh@a1; Wh2 = Wh@a2
//   e[i][j] = leakyrelu(Wh1[i]+Wh2[j]); p = adj>0 ? exp(e) : 0
//   out = (P @ Wh) / rowsum(P)
// Round 22: DECISIVE DRAM-PATTERN EXPERIMENT. Cold-HBM supply is 4.1 TB/s
// vs 5.76 consumed when L3-fed (R17) — last theory standing is that
// 32-interleaved 1KB-granule streams thrash DRAM pages. This kernel makes
// every wave's adj read LINEAR: 2 passes x 16 rows, per half-pass each wave
// streams its 2 rows' 16KB column-halves sequentially into a single-buffered
// [16][4096] P tile (128KB LDS), then a barrier-separated MFMA consume
// phase (B depth-4 reg prefetch from hot L2). If supply doesn't improve,
// R18 (68.6us) is the pattern roofline.

#define NN    8192
#define INF   128
#define OUTF  64
#define BM    32       // rows per block (2 passes x 16)
#define HALF  4096     // cols per half-pass
#define LOG2E 1.4426950408889634f

typedef float  f32x4 __attribute__((ext_vector_type(4)));
typedef int    i32x4 __attribute__((ext_vector_type(4)));
typedef __bf16 bf16x4 __attribute__((ext_vector_type(4)));
typedef __bf16 bf16x8 __attribute__((ext_vector_type(8)));

__device__ __forceinline__ unsigned short f2bf(float x) {
    unsigned u = __builtin_bit_cast(unsigned, x);
    return (unsigned short)((u + 0x7fffu + ((u >> 16) & 1u)) >> 16);
}

// Raw barrier: own LDS ops drained (lgkmcnt(0)), VMEM left in flight.
__device__ __forceinline__ void bar_lgkm_only() {
    asm volatile("s_waitcnt lgkmcnt(0)" ::: "memory");
    __builtin_amdgcn_sched_barrier(0);
    __builtin_amdgcn_s_barrier();
    __builtin_amdgcn_sched_barrier(0);
}

// ---------------- kernel 1: Wh, scaled Wh1/Wh2, packed bf16 Wh (B-frag order)
// (byte-identical to round 6)
__global__ __launch_bounds__(512) void gat_prep(
    const float* __restrict__ h, const float* __restrict__ W,
    const float* __restrict__ a, float* __restrict__ wh1s,
    float* __restrict__ wh2s, unsigned short* __restrict__ whbp)
{
    __shared__ float sWt[64 * 132];   // W transposed [col][k], padded
    __shared__ float sWh[32][64];
    __shared__ float sH[8][128];
    __shared__ float sA[2 * OUTF];
    const int tid = threadIdx.x, lane = tid & 63, wid = tid >> 6;
    const int rb = blockIdx.x;

    for (int idx = tid; idx < INF * OUTF; idx += 512) {
        int k = idx >> 6, c = idx & 63;
        sWt[c * 132 + k] = W[idx];
    }
    if (tid < 2 * OUTF) sA[tid] = a[tid];
    __syncthreads();

    #pragma unroll
    for (int i = 0; i < 4; ++i) {
        const int row = wid * 4 + i;
        const int grow = rb * BM + row;
        sH[wid][lane]      = h[(size_t)grow * INF + lane];
        sH[wid][64 + lane] = h[(size_t)grow * INF + 64 + lane];
        float a0 = 0.f, a1 = 0.f, a2 = 0.f, a3 = 0.f;
        #pragma unroll
        for (int k = 0; k < INF; k += 4) {
            f32x4 wv = *(const f32x4*)(&sWt[lane * 132 + k]);
            f32x4 hv = *(const f32x4*)(&sH[wid][k]);
            a0 = fmaf(hv[0], wv[0], a0);
            a1 = fmaf(hv[1], wv[1], a1);
            a2 = fmaf(hv[2], wv[2], a2);
            a3 = fmaf(hv[3], wv[3], a3);
        }
        float acc = (a0 + a1) + (a2 + a3);
        float v1 = acc * sA[lane];
        float v2 = acc * sA[64 + lane];
        #pragma unroll
        for (int off = 32; off; off >>= 1) {
            v1 += __shfl_xor(v1, off);
            v2 += __shfl_xor(v2, off);
        }
        if (lane == 0) { wh1s[grow] = v1 * LOG2E; wh2s[grow] = v2 * LOG2E; }
        sWh[row][lane] = acc;
    }
    __syncthreads();

    // coalesced whbp chunk write: thread t -> shorts t*4 .. t*4+3
    {
        const int t = tid;
        const int nb  = t >> 7;
        const int lp  = (t & 127) >> 1;
        const int jj0 = (t & 1) * 4;
        const int col = nb * 16 + (lp & 15);
        const int jb  = (lp >> 4) * 8 + jj0;
        unsigned short v[4];
        #pragma unroll
        for (int q = 0; q < 4; ++q) v[q] = f2bf(sWh[jb + q][col]);
        *(uint2*)(whbp + (size_t)rb * 2048 + t * 4) = *(const uint2*)v;
    }
}

// ---------------- kernel 2: linear-stream produce / MFMA consume, 2x16 rows
// 256 blocks x 512 threads (8 waves).
// Produce: wave w owns local rows 2w,2w+1; reads 16KB linear per row-half.
// Consume: wave w = j-slice w*512 within the half; A rows 0..15 from LDS.
__global__ __launch_bounds__(512) void gat_main(
    const int* __restrict__ adj, const float* __restrict__ wh1s,
    const float* __restrict__ wh2s, const unsigned short* __restrict__ whbp,
    float* __restrict__ out)
{
    __shared__ __align__(16) char smem[16 * HALF * 2];  // 128 KB P / sAcc alias
    __shared__ float sRow[16];

    const int tid = threadIdx.x, lane = tid & 63, wid = tid >> 6;
    const int rb = blockIdx.x;
    const int r16 = lane & 15, klo = lane >> 4;
    const int xr = (r16 & 7) << 4;

    for (int p = 0; p < 2; ++p) {
        const int row0 = 2 * wid, row1 = row0 + 1;      // local 0..15
        const int g0 = rb * BM + p * 16 + row0;
        const int* ar0 = adj + (size_t)g0 * NN;
        const int* ar1 = adj + (size_t)(g0 + 1) * NN;
        const float w10 = wh1s[g0], w11 = wh1s[g0 + 1];
        const int x0 = (row0 & 7) << 4, x1 = (row1 & 7) << 4;
        float rs0 = 0.f, rs1 = 0.f;

        f32x4 acc[4];
        #pragma unroll
        for (int nb = 0; nb < 4; ++nb) acc[nb] = (f32x4){0.f, 0.f, 0.f, 0.f};

        for (int hh = 0; hh < 2; ++hh) {
            const int jb = hh * HALF;

            // ---- produce: 16 chunks x (2 rows + wh2), depth-4 prefetch
            struct Chk { i32x4 a0, a1; f32x4 w; };
            Chk C0, C1, C2, C3;
            auto CLOAD = [&](Chk& C, int c) {
                const int off = jb + c * 256 + lane * 4;
                C.a0 = *(const i32x4*)(ar0 + off);
                C.a1 = *(const i32x4*)(ar1 + off);
                C.w  = *(const f32x4*)(wh2s + off);
            };
            auto CPROC = [&](Chk& C, int c) {
                bf16x4 p0, p1;
                #pragma unroll
                for (int u = 0; u < 4; ++u) {
                    float t0 = w10 + C.w[u];
                    float e0 = fmaxf(t0, 0.2f * t0);
                    float v0 = (C.a0[u] > 0) ? __builtin_amdgcn_exp2f(e0) : 0.f;
                    rs0 += v0; p0[u] = (__bf16)v0;
                    float t1 = w11 + C.w[u];
                    float e1 = fmaxf(t1, 0.2f * t1);
                    float v1 = (C.a1[u] > 0) ? __builtin_amdgcn_exp2f(e1) : 0.f;
                    rs1 += v1; p1[u] = (__bf16)v1;
                }
                const int bo = c * 512 + lane * 8;
                *(bf16x4*)(smem + row0 * 8192 + (bo ^ x0)) = p0;
                *(bf16x4*)(smem + row1 * 8192 + (bo ^ x1)) = p1;
            };
            CLOAD(C0, 0); CLOAD(C1, 1); CLOAD(C2, 2); CLOAD(C3, 3);
            #pragma unroll
            for (int c = 0; c < 16; c += 4) {
                CPROC(C0, c);     if (c + 4 < 16) CLOAD(C0, c + 4);
                CPROC(C1, c + 1); if (c + 5 < 16) CLOAD(C1, c + 5);
                CPROC(C2, c + 2); if (c + 6 < 16) CLOAD(C2, c + 6);
                CPROC(C3, c + 3); if (c + 7 < 16) CLOAD(C3, c + 7);
            }
            bar_lgkm_only();   // P(half) visible to all waves

            // ---- consume: 16 K-steps, B depth-4 reg prefetch (L2-hot)
            bf16x8 B0[4], B1[4], B2[4], B3[4];
            auto BLOAD = [&](bf16x8* B, int kk) {
                const unsigned short* bp =
                    whbp + (size_t)(hh * 128 + wid * 16 + kk) * 2048 + lane * 8;
                #pragma unroll
                for (int nb = 0; nb < 4; ++nb)
                    B[nb] = *(const bf16x8*)(bp + nb * 512);
            };
            auto KSTEP = [&](bf16x8* B, int kk) {
                bf16x8 af = *(const bf16x8*)(smem + r16 * 8192 +
                    (((wid * 512 + kk * 32 + klo * 8) * 2) ^ xr));
                #pragma unroll
                for (int nb = 0; nb < 4; ++nb)
                    acc[nb] = __builtin_amdgcn_mfma_f32_16x16x32_bf16(
                        af, B[nb], acc[nb], 0, 0, 0);
            };
            BLOAD(B0, 0); BLOAD(B1, 1); BLOAD(B2, 2); BLOAD(B3, 3);
            #pragma unroll
            for (int kk = 0; kk < 16; kk += 4) {
                KSTEP(B0, kk);     if (kk + 4 < 16) BLOAD(B0, kk + 4);
                KSTEP(B1, kk + 1); if (kk + 5 < 16) BLOAD(B1, kk + 5);
                KSTEP(B2, kk + 2); if (kk + 6 < 16) BLOAD(B2, kk + 6);
                KSTEP(B3, kk + 3); if (kk + 7 < 16) BLOAD(B3, kk + 7);
            }
            bar_lgkm_only();   // WAR: next produce overwrites P
        }

        // per-row softmax denominators (this pass's 16 rows)
        #pragma unroll
        for (int off = 32; off; off >>= 1) {
            rs0 += __shfl_xor(rs0, off);
            rs1 += __shfl_xor(rs1, off);
        }
        if (lane == 0) { sRow[row0] = rs0; sRow[row1] = rs1; }
        __syncthreads();   // sRow visible; P region free for sAcc alias

        // spill acc (C/D layout: row = klo*4 + q, col = nb*16 + r16)
        float* sAcc = (float*)smem;          // [8][1024] = 32 KB
        #pragma unroll
        for (int nb = 0; nb < 4; ++nb) {
            #pragma unroll
            for (int q = 0; q < 4; ++q) {
                int lrow = klo * 4 + q;
                sAcc[wid * 1024 + lrow * 64 + nb * 16 + r16] = acc[nb][q];
            }
        }
        __syncthreads();

        // combine the 8 j-slice waves, divide, write this pass's 16 rows
        for (int idx = tid; idx < 16 * OUTF; idx += 512) {
            int row = idx >> 6, c = idx & 63;
            float s = 0.f;
            #pragma unroll
            for (int w = 0; w < 8; ++w)
                s += sAcc[w * 1024 + row * 64 + c];
            out[(size_t)(rb * BM + p * 16 + row) * OUTF + c] = s / sRow[row];
        }
        if (p == 0) __syncthreads();   // before pass-2 produce overwrites smem
    }
}

extern "C" void kernel_launch(void* const* d_in, const int* in_sizes, int n_in,
                              void* d_out, int out_size, void* d_ws, size_t ws_size,
                              hipStream_t stream) {
    const float* h   = (const float*)d_in[0];
    const float* W   = (const float*)d_in[1];
    const float* a   = (const float*)d_in[2];
    const int*   adj = (const int*)d_in[3];
    float* out = (float*)d_out;

    char* ws = (char*)d_ws;
    unsigned short* whbp = (unsigned short*)ws;             // 1 MB
    float* wh1s = (float*)(ws + (1u << 20));                // 32 KB
    float* wh2s = (float*)(ws + (1u << 20) + 32768);        // 32 KB

    gat_prep<<<NN / BM, 512, 0, stream>>>(h, W, a, wh1s, wh2s, whbp);
    gat_main<<<NN / BM, 512, 0, stream>>>(adj, wh1s, wh2s, whbp, out);
}

// Round 23
// 69.888 us; speedup vs baseline: 1.2303x; 1.2303x over previous
//
#include <hip/hip_runtime.h>

// GAT layer, N=8192, IN_F=128, OUT_F=64.
//   Wh = h@W; Wh1 = Wh@a1; Wh2 = Wh@a2
//   e[i][j] = leakyrelu(Wh1[i]+Wh2[j]); p = adj>0 ? exp(e) : 0
//   out = (P @ Wh) / rowsum(P)
// FINAL (round-18 build, 68.6us): P computed from depth-2-prefetched adj
// regs into swizzled LDS; B fragments register-double-buffered one phase
// ahead; raw s_barrier with lgkmcnt-only drain (counted vmcnt keeps adj
// in flight); fused softmax divide. 16 single-variable experiments + 2
// counter-measurement rounds (R10/R17) show the residual vs the 47us
// ideal is cold-HBM supply (~4.1 TB/s) intrinsic to 8192 concurrent
// row-streams — invariant to granularity, linearity, occupancy, depth,
// barrier semantics, and phase order. This is the pattern's roofline.

#define NN    8192
#define INF   128
#define OUTF  64
#define BM    32       // rows per block
#define RJ    256      // j per round
#define NR    (NN/RJ)  // 32 rounds
#define LOG2E 1.4426950408889634f

typedef float  f32x4 __attribute__((ext_vector_type(4)));
typedef int    i32x4 __attribute__((ext_vector_type(4)));
typedef __bf16 bf16x4 __attribute__((ext_vector_type(4)));
typedef __bf16 bf16x8 __attribute__((ext_vector_type(8)));

__device__ __forceinline__ unsigned short f2bf(float x) {
    unsigned u = __builtin_bit_cast(unsigned, x);
    return (unsigned short)((u + 0x7fffu + ((u >> 16) & 1u)) >> 16);
}

// Raw barrier: own LDS ops drained (lgkmcnt(0)), VMEM left in flight.
__device__ __forceinline__ void bar_lgkm_only() {
    asm volatile("s_waitcnt lgkmcnt(0)" ::: "memory");
    __builtin_amdgcn_sched_barrier(0);
    __builtin_amdgcn_s_barrier();
    __builtin_amdgcn_sched_barrier(0);
}

// ---------------- kernel 1: Wh, scaled Wh1/Wh2, packed bf16 Wh (B-frag order)
__global__ __launch_bounds__(512) void gat_prep(
    const float* __restrict__ h, const float* __restrict__ W,
    const float* __restrict__ a, float* __restrict__ wh1s,
    float* __restrict__ wh2s, unsigned short* __restrict__ whbp)
{
    __shared__ float sWt[64 * 132];   // W transposed [col][k], padded
    __shared__ float sWh[32][64];
    __shared__ float sH[8][128];
    __shared__ float sA[2 * OUTF];
    const int tid = threadIdx.x, lane = tid & 63, wid = tid >> 6;
    const int rb = blockIdx.x;

    for (int idx = tid; idx < INF * OUTF; idx += 512) {
        int k = idx >> 6, c = idx & 63;
        sWt[c * 132 + k] = W[idx];
    }
    if (tid < 2 * OUTF) sA[tid] = a[tid];
    __syncthreads();

    #pragma unroll
    for (int i = 0; i < 4; ++i) {
        const int row = wid * 4 + i;
        const int grow = rb * BM + row;
        sH[wid][lane]      = h[(size_t)grow * INF + lane];
        sH[wid][64 + lane] = h[(size_t)grow * INF + 64 + lane];
        float a0 = 0.f, a1 = 0.f, a2 = 0.f, a3 = 0.f;
        #pragma unroll
        for (int k = 0; k < INF; k += 4) {
            f32x4 wv = *(const f32x4*)(&sWt[lane * 132 + k]);
            f32x4 hv = *(const f32x4*)(&sH[wid][k]);
            a0 = fmaf(hv[0], wv[0], a0);
            a1 = fmaf(hv[1], wv[1], a1);
            a2 = fmaf(hv[2], wv[2], a2);
            a3 = fmaf(hv[3], wv[3], a3);
        }
        float acc = (a0 + a1) + (a2 + a3);
        float v1 = acc * sA[lane];
        float v2 = acc * sA[64 + lane];
        #pragma unroll
        for (int off = 32; off; off >>= 1) {
            v1 += __shfl_xor(v1, off);
            v2 += __shfl_xor(v2, off);
        }
        if (lane == 0) { wh1s[grow] = v1 * LOG2E; wh2s[grow] = v2 * LOG2E; }
        sWh[row][lane] = acc;
    }
    __syncthreads();

    // coalesced whbp chunk write: thread t -> shorts t*4 .. t*4+3
    {
        const int t = tid;
        const int nb  = t >> 7;
        const int lp  = (t & 127) >> 1;
        const int jj0 = (t & 1) * 4;
        const int col = nb * 16 + (lp & 15);
        const int jb  = (lp >> 4) * 8 + jj0;
        unsigned short v[4];
        #pragma unroll
        for (int q = 0; q < 4; ++q) v[q] = f2bf(sWh[jb + q][col]);
        *(uint2*)(whbp + (size_t)rb * 2048 + t * 4) = *(const uint2*)v;
    }
}

// ---------------- kernel 2: P via swizzled LDS, B via register double-buffer
// 256 blocks x 512 threads (8 waves). Phase A: wave w owns rows 4w..4w+3.
// Phase B: wave w = (rh=w>>2, js=w&3) -> rows rh*16..+15, j-slice js*64..+63.
__global__ __launch_bounds__(512) void gat_main(
    const int* __restrict__ adj, const float* __restrict__ wh1s,
    const float* __restrict__ wh2s, const unsigned short* __restrict__ whbp,
    float* __restrict__ out)
{
    __shared__ __align__(16) char smem[2 * BM * RJ * 2];  // 32 KB P dbuf / sAcc alias
    __shared__ float sRow[BM];

    const int tid = threadIdx.x, lane = tid & 63, wid = tid >> 6;
    const int rb = blockIdx.x;
    const int r16 = lane & 15, klo = lane >> 4;

    // phase-A role: 4 rows per wave
    const int ra0 = 4 * wid;
    const int* adjr[4];
    float wh1v[4];
    int xw[4];
    #pragma unroll
    for (int r = 0; r < 4; ++r) {
        const int grow = rb * BM + ra0 + r;
        adjr[r] = adj + (size_t)grow * NN;
        wh1v[r] = wh1s[grow];
        xw[r]   = ((ra0 + r) & 7) << 4;
    }

    // phase-B role
    const int rh = wid >> 2, js = wid & 3;
    const int rloc = rh * 16 + r16;
    const int xr = (rloc & 7) << 4;

    f32x4 acc[4];
    #pragma unroll
    for (int nb = 0; nb < 4; ++nb) acc[nb] = (f32x4){0.f, 0.f, 0.f, 0.f};
    float rs[4] = {0.f, 0.f, 0.f, 0.f};

    struct AdjSet { i32x4 a[4]; f32x4 w; };
    AdjSet S0, S1;
    bf16x8 B0[8], B1[8];   // B frag double-buffer in registers (static idx only)

    auto LOADA = [&](AdjSet& S, int rr) {
        const int jb = rr * RJ + lane * 4;
        #pragma unroll
        for (int r = 0; r < 4; ++r)
            S.a[r] = *(const i32x4*)(adjr[r] + jb);
        S.w = *(const f32x4*)(wh2s + jb);
    };

    // load this wave's B frags for round rr straight to registers
    auto BLOADG = [&](bf16x8* B, int rr) {
        #pragma unroll
        for (int kk = 0; kk < 2; ++kk) {
            const unsigned short* bp =
                whbp + (size_t)(rr * 8 + js * 2 + kk) * 2048 + lane * 8;
            #pragma unroll
            for (int nb = 0; nb < 4; ++nb)
                B[kk * 4 + nb] = *(const bf16x8*)(bp + nb * 512);
        }
    };

    auto PROC = [&](i32x4 ad, f32x4 w2, float w1, float& rsum) -> bf16x4 {
        bf16x4 o;
        #pragma unroll
        for (int u = 0; u < 4; ++u) {
            float tt = w1 + w2[u];
            float e  = fmaxf(tt, 0.2f * tt);             // leaky (log2 domain)
            float p  = (ad[u] > 0) ? __builtin_amdgcn_exp2f(e) : 0.f;
            rsum += p;
            o[u] = (__bf16)p;
        }
        return o;
    };

    auto STORE = [&](int rr, AdjSet& S) {   // produce P(rr) into P half rr&1
        char* Pb = smem + ((rr & 1) << 14);
        #pragma unroll
        for (int r = 0; r < 4; ++r) {
            bf16x4 p = PROC(S.a[r], S.w, wh1v[r], rs[r]);
            *(bf16x4*)(Pb + (ra0 + r) * 512 + ((lane * 8) ^ xw[r])) = p;
        }
    };

    // PHASE(rr): bar -> BLOADG(rr+1 into Bnext) -> STORE(rr+1) -> LOADA(rr+3)
    //            -> MFMA(rr) [P from LDS, B from Bcur regs, counted vmcnt]
    auto PHASE = [&](int rr, AdjSet& Scons, bf16x8* Bcur, bf16x8* Bnext) {
        bar_lgkm_only();                 // P(rr) visible; VMEM stays in flight

        if (rr + 1 < NR) {
            BLOADG(Bnext, rr + 1);
            STORE(rr + 1, Scons);
            if (rr + 3 < NR) LOADA(Scons, rr + 3);
        }

        const char* Pb = smem + ((rr & 1) << 14);
        #pragma unroll
        for (int kk = 0; kk < 2; ++kk) {
            bf16x8 af = *(const bf16x8*)(Pb + rloc * 512 +
                ((js * 128 + kk * 64 + klo * 16) ^ xr));
            #pragma unroll
            for (int nb = 0; nb < 4; ++nb)
                acc[nb] = __builtin_amdgcn_mfma_f32_16x16x32_bf16(
                    af, Bcur[kk * 4 + nb], acc[nb], 0, 0, 0);
        }
    };

    // prologue: adj depth-2, B(0) in regs, P(0) in LDS
    LOADA(S0, 0);
    LOADA(S1, 1);
    BLOADG(B0, 0);
    STORE(0, S0);
    LOADA(S0, 2);

    for (int rr = 0; rr < NR; rr += 2) {
        PHASE(rr,     S1, B0, B1);   // consume B(rr),   load B(rr+1)
        PHASE(rr + 1, S0, B1, B0);   // consume B(rr+1), load B(rr+2)
    }

    // per-row softmax denominators
    #pragma unroll
    for (int r = 0; r < 4; ++r) {
        float v = rs[r];
        #pragma unroll
        for (int off = 32; off; off >>= 1) v += __shfl_xor(v, off);
        if (lane == 0) sRow[ra0 + r] = v;
    }

    __syncthreads();   // cold: full drain fine; safe to alias smem as sAcc

    // spill acc (C/D layout: row = klo*4 + q, col = nb*16 + r16)
    float* sAcc = (float*)smem;          // [8][1024] = 32 KB (P region)
    #pragma unroll
    for (int nb = 0; nb < 4; ++nb) {
        #pragma unroll
        for (int q = 0; q < 4; ++q) {
            int lrow = klo * 4 + q;
            sAcc[wid * 1024 + lrow * 64 + nb * 16 + r16] = acc[nb][q];
        }
    }
    __syncthreads();

    // combine the 4 j-slice waves per rowhalf, divide, write out
    for (int idx = tid; idx < BM * OUTF; idx += 512) {
        int row = idx >> 6, c = idx & 63, rhh = row >> 4;
        float s = 0.f;
        #pragma unroll
        for (int j4 = 0; j4 < 4; ++j4)
            s += sAcc[(rhh * 4 + j4) * 1024 + (row & 15) * 64 + c];
        out[(size_t)(rb * BM + row) * OUTF + c] = s / sRow[row];
    }
}

extern "C" void kernel_launch(void* const* d_in, const int* in_sizes, int n_in,
                              void* d_out, int out_size, void* d_ws, size_t ws_size,
                              hipStream_t stream) {
    const float* h   = (const float*)d_in[0];
    const float* W   = (const float*)d_in[1];
    const float* a   = (const float*)d_in[2];
    const int*   adj = (const int*)d_in[3];
    float* out = (float*)d_out;

    char* ws = (char*)d_ws;
    unsigned short* whbp = (unsigned short*)ws;             // 1 MB
    float* wh1s = (float*)(ws + (1u << 20));                // 32 KB
    float* wh2s = (float*)(ws + (1u << 20) + 32768);        // 32 KB

    gat_prep<<<NN / BM, 512, 0, stream>>>(h, W, a, wh1s, wh2s, whbp);
    gat_main<<<NN / BM, 512, 0, stream>>>(adj, wh1s, wh2s, whbp, out);
}